// Round 9
// baseline (199.970 us; speedup 1.0000x reference)
//
#include <hip/hip_runtime.h>
#include <hip/hip_bf16.h>

#define B_ 16
#define S_ 4096
#define C_ 320
#define KK_ 77
#define D_ 768
#define H_ 8
#define DH_ 40
#define KP_ 80           // padded keys per head
#define NP_ (H_ * KP_)   // 640
#define TAU_ 0.1f
#define GAMMA_ 1.0f
#define EPS_ 1e-12f

typedef __bf16 bf16x8 __attribute__((ext_vector_type(8)));
typedef float f32x4 __attribute__((ext_vector_type(4)));
typedef unsigned short ushort8v __attribute__((ext_vector_type(8)));
typedef unsigned int u32;

#define WAITV(N)  asm volatile("s_waitcnt vmcnt(" #N ")" ::: "memory")
#define WAITVL(N) asm volatile("s_waitcnt vmcnt(" #N ") lgkmcnt(0)" ::: "memory")
#define WAITLG()  asm volatile("s_waitcnt lgkmcnt(0)" ::: "memory")
#define BAR()     __builtin_amdgcn_s_barrier()

__device__ __forceinline__ unsigned short f2bf(float f) {
    union { float f; unsigned u; } v; v.f = f;
    unsigned r = v.u + 0x7fffu + ((v.u >> 16) & 1u);
    return (unsigned short)(r >> 16);
}

// async 16B-per-lane global->LDS DMA (lds dest = wave-uniform base + lane*16)
__device__ __forceinline__ void gld16(const unsigned short* g, char* l) {
    __builtin_amdgcn_global_load_lds(
        (const __attribute__((address_space(1))) u32*)g,
        (__attribute__((address_space(3))) u32*)l, 16, 0, 0);
}

// ---------------------------------------------------------------- build_M
__global__ __launch_bounds__(256) void build_M(const float* __restrict__ Wq,
        const float* __restrict__ Wk, const float* __restrict__ Wv,
        const float* __restrict__ Wo, unsigned short* __restrict__ Bmat) {
    const int Dk = blockIdx.x * 256 + threadIdx.x;     // 0..767
    const int h = blockIdx.y;
    const int which = blockIdx.z >> 2;
    const int c0 = (blockIdx.z & 3) * 80;
    __shared__ float wlds[80 * 44];
    for (int i = threadIdx.x; i < 80 * DH_; i += 256) {
        int c = i / DH_, d = i % DH_;
        wlds[c * 44 + d] = which
            ? Wo[(size_t)(h * DH_ + d) * C_ + (c0 + c)]
            : Wq[(size_t)(c0 + c) * C_ + h * DH_ + d];
    }
    float a[DH_];
    const float* Arow = (which ? Wv : Wk) + (size_t)Dk * C_ + h * DH_;
    #pragma unroll
    for (int d = 0; d < DH_; ++d) a[d] = Arow[d];
    __syncthreads();
    const float scale = 0.15811388300841898f;          // 1/sqrt(40)
    for (int c = 0; c < 80; ++c) {
        float s = 0.f;
        #pragma unroll
        for (int q = 0; q < 10; ++q) {
            float4 wv4 = *(const float4*)&wlds[c * 44 + q * 4];
            s += a[q * 4 + 0] * wv4.x + a[q * 4 + 1] * wv4.y
               + a[q * 4 + 2] * wv4.z + a[q * 4 + 3] * wv4.w;
        }
        if (!which) s *= scale;
        int n = which * 2560 + h * C_ + c0 + c;
        Bmat[(size_t)n * D_ + Dk] = f2bf(s);
    }
}

// ---------------------------------------------------------------- prep_ehs
__global__ __launch_bounds__(256) void prep_ehs(const float* __restrict__ ehs,
        const float* __restrict__ harm, unsigned short* __restrict__ ehs_bf,
        float* __restrict__ pen) {
    const int w = threadIdx.x >> 6, l = threadIdx.x & 63;
    const int kk = blockIdx.x * 4 + w, b = blockIdx.y;
    const size_t obase = ((size_t)b * KP_ + kk) * D_;
    if (kk >= KK_) {
        #pragma unroll
        for (int j = 0; j < 12; ++j) ehs_bf[obase + l + j * 64] = 0;
        if (l == 0) pen[b * KP_ + kk] = 0.f;
        return;
    }
    const float* er = ehs + ((size_t)b * KK_ + kk) * D_;
    float ss = 0.f, dd = 0.f, hh = 0.f;
    #pragma unroll
    for (int j = 0; j < 12; ++j) {
        float e = er[l + j * 64], hv = harm[l + j * 64];
        ehs_bf[obase + l + j * 64] = f2bf(e);
        ss += e * e; dd += e * hv; hh += hv * hv;
    }
    #pragma unroll
    for (int off = 32; off; off >>= 1) {
        ss += __shfl_xor(ss, off);
        dd += __shfl_xor(dd, off);
        hh += __shfl_xor(hh, off);
    }
    if (l == 0) {
        float cs = dd / (fmaxf(sqrtf(ss), EPS_) * fmaxf(sqrtf(hh), EPS_));
        pen[b * KP_ + kk] = GAMMA_ * fmaxf(cs - TAU_, 0.f);
    }
}

// ---------------------------------------------------------------- gemm_WpU
__global__ __launch_bounds__(1024) void gemm_WpU(
        const unsigned short* __restrict__ ehs_bf,
        const unsigned short* __restrict__ Bmat,
        unsigned short* __restrict__ Wp, unsigned short* __restrict__ U) {
    const int id = blockIdx.x;               // 160 = 16 b * 10 nt
    const int b = id & 15, nt = id >> 4;
    const int tid = threadIdx.x, w = tid >> 6, l = tid & 63;
    const int lrow = l & 15, lgrp = l >> 4, lk = lgrp * 8;
    __shared__ unsigned short Al[80 * 768];  // 122880 B, swizzled
    char* lds = (char*)Al;

    const unsigned short* Ag = ehs_bf + (size_t)b * KP_ * D_;
    #pragma unroll
    for (int it = 0; it < 8; ++it) {
        int ch = tid + it * 1024;
        if (ch < 7680) {
            int byte = ch * 16, row = byte / 1536;
            int a = byte ^ ((row & 7) << 4);
            *(ushort8v*)(lds + a) = *(const ushort8v*)(Ag + ch * 8);
        }
    }
    const int n0 = nt * 512 + w * 32;
    const unsigned short* Br = Bmat + (size_t)(n0 + lrow) * D_ + lk;
    bf16x8 bC[2], bN[2];
    #pragma unroll
    for (int nf = 0; nf < 2; ++nf)
        bC[nf] = *(const bf16x8*)(Br + (size_t)nf * 16 * D_);
    __syncthreads();

    f32x4 acc[5][2];
    #pragma unroll
    for (int mf = 0; mf < 5; ++mf)
        #pragma unroll
        for (int nf = 0; nf < 2; ++nf) acc[mf][nf] = (f32x4){0.f, 0.f, 0.f, 0.f};
    #pragma unroll
    for (int ks = 0; ks < D_ / 32; ++ks) {
        if (ks < D_ / 32 - 1) {
            #pragma unroll
            for (int nf = 0; nf < 2; ++nf)
                bN[nf] = *(const bf16x8*)(Br + (size_t)nf * 16 * D_ + (ks + 1) * 32);
        }
        bf16x8 af[5];
        #pragma unroll
        for (int mf = 0; mf < 5; ++mf) {
            int row = mf * 16 + lrow;
            int a = (row * 1536 + (ks * 32 + lk) * 2) ^ ((row & 7) << 4);
            af[mf] = *(const bf16x8*)(lds + a);
        }
        __builtin_amdgcn_s_setprio(1);
        #pragma unroll
        for (int mf = 0; mf < 5; ++mf)
            #pragma unroll
            for (int nf = 0; nf < 2; ++nf)
                acc[mf][nf] = __builtin_amdgcn_mfma_f32_16x16x32_bf16(
                    af[mf], bC[nf], acc[mf][nf], 0, 0, 0);
        __builtin_amdgcn_s_setprio(0);
        #pragma unroll
        for (int nf = 0; nf < 2; ++nf) bC[nf] = bN[nf];
    }
    #pragma unroll
    for (int nf = 0; nf < 2; ++nf) {
        const int col = n0 + nf * 16 + lrow;
        if (col < 2560) {
            const int h = col / C_, c = col % C_;
            #pragma unroll
            for (int mf = 0; mf < 5; ++mf)
                #pragma unroll
                for (int r = 0; r < 4; ++r) {
                    int kk = mf * 16 + lgrp * 4 + r;
                    Wp[((size_t)b * NP_ + h * KP_ + kk) * C_ + c] = f2bf(acc[mf][nf][r]);
                }
        } else {
            const int n2 = col - 2560;
            const int h = n2 / C_, c = n2 % C_;
            #pragma unroll
            for (int mf = 0; mf < 5; ++mf)
                #pragma unroll
                for (int r = 0; r < 4; ++r) {
                    int kk = mf * 16 + lgrp * 4 + r;
                    U[((size_t)b * C_ + c) * NP_ + h * KP_ + kk] = f2bf(acc[mf][nf][r]);
                }
        }
    }
}

// ---------------------------------------------------------------- fused attn
// 1024 blocks x 1024 threads, 64 S-rows, 160KB LDS, depth-2 DMA pipeline.
// Phase 1: HS 40KB + 3x40KB Wp bufs, 10 K=32 slices, slices k+1..k+3 in flight.
// Phase 2: two head-half passes; P-half 40KB + 3x40KB U bufs, K=64 slices,
//          5 iters/pass. P packed in regs until its pass; acc2 spans passes.
__global__ __launch_bounds__(1024) void fused_attn(
        const float* __restrict__ hs, const unsigned short* __restrict__ Wp,
        const unsigned short* __restrict__ U, const float* __restrict__ pen,
        const float* __restrict__ bo, float* __restrict__ out) {
    const int id = blockIdx.x;                  // 1024 = 8 xcd * 128
    const int xcd = id & 7, rest = id >> 3;
    const int b = xcd * 2 + (rest >> 6);        // 2 batches per XCD
    const int s0 = (rest & 63) * 64;
    __shared__ __align__(16) char smem[163840];
    char* HS  = smem;                           // phase1 hs tile / phase2 P-half
    char* BUF0 = smem + 40960;
    char* BUF1 = smem + 81920;
    char* BUF2 = smem + 122880;
    const int tid = threadIdx.x, w = tid >> 6, l = tid & 63;
    const int lrow = l & 15, lgrp = l >> 4, lk = lgrp * 8;
    const int h = w & 7, mh = w >> 3;           // phase-1 roles
    const int mgrp = w & 3, ngrp = w >> 2;      // phase-2 roles

    const unsigned short* Wpb = Wp + (size_t)b * NP_ * C_;
    const unsigned short* Ub  = U  + (size_t)b * C_ * NP_;

    // Wp K=32 slice -> [n 640][4 chunks 16B], chunk swz ^((n>>1)&3) on source.
    // per-wave DMA insts: 3 (w<8) / 2 (w>=8)
    auto stage_wp = [&](int ks, char* buf) {
        #pragma unroll
        for (int j = 0; j < 2; ++j) {
            int L = w * 128 + j * 64 + l;       // 0..2047
            int n = L >> 2, cs = (L & 3) ^ ((n >> 1) & 3);
            gld16(Wpb + (size_t)n * C_ + ks * 32 + cs * 8,
                  buf + (w * 128 + j * 64) * 16);
        }
        if (w < 8) {
            int L = 2048 + w * 64 + l;          // 2048..2559
            int n = L >> 2, cs = (L & 3) ^ ((n >> 1) & 3);
            gld16(Wpb + (size_t)n * C_ + ks * 32 + cs * 8,
                  buf + (2048 + w * 64) * 16);
        }
    };
    // U K=64 slice (pass p, slice t) -> [c 320][8 chunks 16B], swz ^(c&7).
    // per-wave DMA insts: 3 (w<8) / 2 (w>=8)
    auto stage_u = [&](int p, int t, char* buf) {
        const int k0 = p * 320 + t * 64;        // short offset in U row
        #pragma unroll
        for (int j = 0; j < 2; ++j) {
            int L = w * 128 + j * 64 + l;       // 0..2047
            int c = L >> 3, s2 = (L & 7) ^ (c & 7);
            gld16(Ub + (size_t)c * NP_ + k0 + s2 * 8,
                  buf + (w * 128 + j * 64) * 16);
        }
        if (w < 8) {
            int L = 2048 + w * 64 + l;          // 2048..2559
            int c = L >> 3, s2 = (L & 7) ^ (c & 7);
            gld16(Ub + (size_t)c * NP_ + k0 + s2 * 8,
                  buf + (2048 + w * 64) * 16);
        }
    };

    // ---- prologue: DMA slices 0..2, then pen + hs staging under the DMA
    stage_wp(0, BUF0);
    stage_wp(1, BUF1);
    stage_wp(2, BUF2);
    float4 pv4[5];
    #pragma unroll
    for (int nf = 0; nf < 5; ++nf)
        pv4[nf] = *(const float4*)(pen + b * KP_ + nf * 16 + lgrp * 4);
    const float4* hv = (const float4*)(hs + ((size_t)b * S_ + s0) * C_);
    #pragma unroll
    for (int it = 0; it < 5; ++it) {            // 5*1024 = 5120 float4 = 64x320 f32
        int i = tid + it * 1024;
        float4 v = hv[i];
        int r = i / 80, c = (i * 4) % C_;
        ushort4 u;
        u.x = f2bf(v.x); u.y = f2bf(v.y); u.z = f2bf(v.z); u.w = f2bf(v.w);
        int a = (r * 640 + c * 2) ^ ((r & 7) << 4);
        *(ushort4*)(HS + a) = u;
    }
    #pragma unroll
    for (int nf = 0; nf < 5; ++nf)              // retire pen loads (vmcnt purity)
        asm volatile("" :: "v"(pv4[nf].x), "v"(pv4[nf].y),
                           "v"(pv4[nf].z), "v"(pv4[nf].w));
    if (w < 8) { WAITVL(6); } else { WAITVL(4); }   // slice0 landed + ds_writes done
    BAR();

    // ---- phase 1: D[kk][m] over 10 K-slices, 3-buf depth-2 pipeline
    f32x4 acc[5][2];
    #pragma unroll
    for (int nf = 0; nf < 5; ++nf)
        #pragma unroll
        for (int mf = 0; mf < 2; ++mf) acc[nf][mf] = (f32x4){0.f, 0.f, 0.f, 0.f};
    #pragma unroll
    for (int ks = 0; ks < 10; ++ks) {
        char* wb = (ks % 3 == 0) ? BUF0 : (ks % 3 == 1) ? BUF1 : BUF2;
        bf16x8 bC[5], hf[2];
        #pragma unroll
        for (int nf = 0; nf < 5; ++nf) {
            int n = h * KP_ + nf * 16 + lrow;
            bC[nf] = *(const bf16x8*)(wb + n * 64 + ((lgrp ^ ((n >> 1) & 3)) << 4));
        }
        #pragma unroll
        for (int mf = 0; mf < 2; ++mf) {
            int row = mh * 32 + mf * 16 + lrow;
            int a = (row * 640 + (ks * 32 + lk) * 2) ^ ((row & 7) << 4);
            hf[mf] = *(const bf16x8*)(HS + a);
        }
        WAITLG();
        BAR();                                  // all waves done reading wb
        if (ks < 7) stage_wp(ks + 3, wb);       // refill freed buffer (depth-2)
        __builtin_amdgcn_s_setprio(1);
        #pragma unroll
        for (int nf = 0; nf < 5; ++nf)
            #pragma unroll
            for (int mf = 0; mf < 2; ++mf)
                acc[nf][mf] = __builtin_amdgcn_mfma_f32_16x16x32_bf16(
                    bC[nf], hf[mf], acc[nf][mf], 0, 0, 0);
        __builtin_amdgcn_s_setprio(0);
        if (ks < 9) {
            if (ks < 7)      { if (w < 8) { WAITV(6); } else { WAITV(4); } }
            else if (ks == 7){ if (w < 8) { WAITV(3); } else { WAITV(2); } }
            else             { WAITV(0); }
            BAR();                              // slice ks+1 visible to all
        }
    }
    // iter-9 BAR came from its read-barrier; HS and all bufs now free.

    // ---- transition: stage pass-A U slices; softmax + P-A write overlap DMA
    stage_u(0, 0, BUF0);
    stage_u(0, 1, BUF1);
    stage_u(0, 2, BUF2);

    float inv2[2];
    #pragma unroll
    for (int mf = 0; mf < 2; ++mf) {
        float mx = -1e30f;
        #pragma unroll
        for (int nf = 0; nf < 5; ++nf)
            #pragma unroll
            for (int r = 0; r < 4; ++r) {
                float x = acc[nf][mf][r] - ((const float*)&pv4[nf])[r];
                if (nf == 4 && r >= 1) x = (lgrp == 3) ? -1e30f : x;  // kk 77..79
                acc[nf][mf][r] = x;
                mx = fmaxf(mx, x);
            }
        mx = fmaxf(mx, __shfl_xor(mx, 16));
        mx = fmaxf(mx, __shfl_xor(mx, 32));
        float s = 0.f;
        #pragma unroll
        for (int nf = 0; nf < 5; ++nf)
            #pragma unroll
            for (int r = 0; r < 4; ++r) {
                float e = __expf(acc[nf][mf][r] - mx);
                acc[nf][mf][r] = e; s += e;
            }
        s += __shfl_xor(s, 16);
        s += __shfl_xor(s, 32);
        inv2[mf] = 1.f / s;
    }
    // pack P to bf16 in registers (20 VGPRs), held until this head's pass
    ushort4 pk[2][5];
    #pragma unroll
    for (int mf = 0; mf < 2; ++mf)
        #pragma unroll
        for (int nf = 0; nf < 5; ++nf) {
            pk[mf][nf].x = f2bf(acc[nf][mf][0] * inv2[mf]);
            pk[mf][nf].y = f2bf(acc[nf][mf][1] * inv2[mf]);
            pk[mf][nf].z = f2bf(acc[nf][mf][2] * inv2[mf]);
            pk[mf][nf].w = f2bf(acc[nf][mf][3] * inv2[mf]);
        }
    // P-half write, pass A (heads 0..3): byte = (m*640 + col*2) ^ ((m&7)<<4)
    if ((h >> 2) == 0) {
        #pragma unroll
        for (int mf = 0; mf < 2; ++mf) {
            int m = mh * 32 + mf * 16 + lrow;
            #pragma unroll
            for (int nf = 0; nf < 5; ++nf) {
                int col = (h & 3) * KP_ + nf * 16 + lgrp * 4;
                *(ushort4*)(HS + ((m * 640 + col * 2) ^ ((m & 7) << 4))) = pk[mf][nf];
            }
        }
    }
    if (w < 8) { WAITVL(6); } else { WAITVL(4); }   // U-A slice0 landed + P-A visible
    BAR();

    // ---- phase 2: out = P @ U + bo ; two passes x 5 K=64-slice iterations
    f32x4 acc2[5];
    #pragma unroll
    for (int nf = 0; nf < 5; ++nf) acc2[nf] = (f32x4){0.f, 0.f, 0.f, 0.f};
    #pragma unroll
    for (int p = 0; p < 2; ++p) {
        #pragma unroll
        for (int t = 0; t < 5; ++t) {
            char* ub = (t % 3 == 0) ? BUF0 : (t % 3 == 1) ? BUF1 : BUF2;
            bf16x8 pa[2], uf[5][2];
            #pragma unroll
            for (int ks2 = 0; ks2 < 2; ++ks2) {
                int m = mgrp * 16 + lrow;
                int abyte = (m * 640 + (t * 64 + ks2 * 32 + lgrp * 8) * 2)
                            ^ ((m & 7) << 4);
                pa[ks2] = *(const bf16x8*)(HS + abyte);
            }
            #pragma unroll
            for (int nf = 0; nf < 5; ++nf) {
                int c = ngrp * KP_ + nf * 16 + lrow;
                #pragma unroll
                for (int ks2 = 0; ks2 < 2; ++ks2) {
                    int s2 = (ks2 * 4 + lgrp) ^ (c & 7);
                    uf[nf][ks2] = *(const bf16x8*)(ub + c * 128 + s2 * 16);
                }
            }
            WAITLG();
            BAR();                              // all waves done reading ub
            if (t < 2) stage_u(p, t + 3, ub);   // depth-2 refill
            __builtin_amdgcn_s_setprio(1);
            #pragma unroll
            for (int nf = 0; nf < 5; ++nf)
                #pragma unroll
                for (int ks2 = 0; ks2 < 2; ++ks2)
                    acc2[nf] = __builtin_amdgcn_mfma_f32_16x16x32_bf16(
                        pa[ks2], uf[nf][ks2], acc2[nf], 0, 0, 0);
            __builtin_amdgcn_s_setprio(0);
            if (p == 1 && t == 4) break;        // epilogue next, no more waits
            if (t < 4) {
                if (t < 2)       { if (w < 8) { WAITV(6); } else { WAITV(4); } }
                else if (t == 2) { if (w < 8) { WAITV(3); } else { WAITV(2); } }
                else             { WAITV(0); }
                BAR();                          // slice t+1 visible to all
            }
        }
        if (p == 0) {
            // transition A->B: last read-barrier already certified buffers/P free
            stage_u(1, 0, BUF0);
            stage_u(1, 1, BUF1);
            stage_u(1, 2, BUF2);
            if ((h >> 2) == 1) {                // P-half write, pass B (heads 4..7)
                #pragma unroll
                for (int mf = 0; mf < 2; ++mf) {
                    int m = mh * 32 + mf * 16 + lrow;
                    #pragma unroll
                    for (int nf = 0; nf < 5; ++nf) {
                        int col = (h & 3) * KP_ + nf * 16 + lgrp * 4;
                        *(ushort4*)(HS + ((m * 640 + col * 2) ^ ((m & 7) << 4))) = pk[mf][nf];
                    }
                }
            }
            if (w < 8) { WAITVL(6); } else { WAITVL(4); }  // U-B slice0 + P-B visible
            BAR();
        }
    }

    // ---- epilogue
    float bov[5];
    #pragma unroll
    for (int nf = 0; nf < 5; ++nf) bov[nf] = bo[ngrp * KP_ + nf * 16 + lrow];
    float* op = out + ((size_t)b * S_ + s0) * C_;
    #pragma unroll
    for (int r = 0; r < 4; ++r)
        #pragma unroll
        for (int nf = 0; nf < 5; ++nf)
            op[(size_t)(mgrp * 16 + lgrp * 4 + r) * C_ +
               ngrp * KP_ + nf * 16 + lrow] = acc2[nf][r] + bov[nf];
}

// ---------------------------------------------------------------- launch
extern "C" void kernel_launch(void* const* d_in, const int* in_sizes, int n_in,
                              void* d_out, int out_size, void* d_ws, size_t ws_size,
                              hipStream_t stream) {
    const float* hs   = (const float*)d_in[0];
    const float* ehs  = (const float*)d_in[1];
    const float* harm = (const float*)d_in[2];
    const float* Wq   = (const float*)d_in[3];
    const float* Wk   = (const float*)d_in[4];
    const float* Wv   = (const float*)d_in[5];
    const float* Wo   = (const float*)d_in[6];
    const float* bo   = (const float*)d_in[7];
    float* out = (float*)d_out;

    char* ws = (char*)d_ws;
    unsigned short* ehs_bf = (unsigned short*)(ws);             //  1,966,080
    unsigned short* Bmat   = (unsigned short*)(ws + 1966080);   //  7,864,320
    float*          pen    = (float*)        (ws + 9830400);    //      5,120
    unsigned short* Wp     = (unsigned short*)(ws + 9835520);   //  6,553,600
    unsigned short* U      = (unsigned short*)(ws + 16389120);  //  6,553,600

    build_M <<<dim3(3, 8, 8),  256, 0, stream>>>(Wq, Wk, Wv, Wo, Bmat);
    prep_ehs<<<dim3(20, 16),   256, 0, stream>>>(ehs, harm, ehs_bf, pen);
    gemm_WpU<<<dim3(160),     1024, 0, stream>>>(ehs_bf, Bmat, Wp, U);
    fused_attn<<<dim3(1024),  1024, 0, stream>>>(hs, Wp, U, pen, bo, out);
}

// Round 10
// 173.597 us; speedup vs baseline: 1.1519x; 1.1519x over previous
//
#include <hip/hip_runtime.h>
#include <hip/hip_bf16.h>

#define B_ 16
#define S_ 4096
#define C_ 320
#define KK_ 77
#define D_ 768
#define H_ 8
#define DH_ 40
#define KP_ 80           // padded keys per head
#define NP_ (H_ * KP_)   // 640
#define TAU_ 0.1f
#define GAMMA_ 1.0f
#define EPS_ 1e-12f

typedef __bf16 bf16x8 __attribute__((ext_vector_type(8)));
typedef float f32x4 __attribute__((ext_vector_type(4)));
typedef unsigned short ushort8v __attribute__((ext_vector_type(8)));
typedef unsigned int u32;

#define WAITV(N)  asm volatile("s_waitcnt vmcnt(" #N ")" ::: "memory")
#define WAITVL(N) asm volatile("s_waitcnt vmcnt(" #N ") lgkmcnt(0)" ::: "memory")
#define WAITLG()  asm volatile("s_waitcnt lgkmcnt(0)" ::: "memory")
#define BAR()     __builtin_amdgcn_s_barrier()

__device__ __forceinline__ unsigned short f2bf(float f) {
    union { float f; unsigned u; } v; v.f = f;
    unsigned r = v.u + 0x7fffu + ((v.u >> 16) & 1u);
    return (unsigned short)(r >> 16);
}

// async 16B-per-lane global->LDS DMA (lds dest = wave-uniform base + lane*16)
__device__ __forceinline__ void gld16(const unsigned short* g, char* l) {
    __builtin_amdgcn_global_load_lds(
        (const __attribute__((address_space(1))) u32*)g,
        (__attribute__((address_space(3))) u32*)l, 16, 0, 0);
}

// ---------------------------------------------------------------- build_M
__global__ __launch_bounds__(256) void build_M(const float* __restrict__ Wq,
        const float* __restrict__ Wk, const float* __restrict__ Wv,
        const float* __restrict__ Wo, unsigned short* __restrict__ Bmat) {
    const int Dk = blockIdx.x * 256 + threadIdx.x;     // 0..767
    const int h = blockIdx.y;
    const int which = blockIdx.z >> 2;
    const int c0 = (blockIdx.z & 3) * 80;
    __shared__ float wlds[80 * 44];
    for (int i = threadIdx.x; i < 80 * DH_; i += 256) {
        int c = i / DH_, d = i % DH_;
        wlds[c * 44 + d] = which
            ? Wo[(size_t)(h * DH_ + d) * C_ + (c0 + c)]
            : Wq[(size_t)(c0 + c) * C_ + h * DH_ + d];
    }
    float a[DH_];
    const float* Arow = (which ? Wv : Wk) + (size_t)Dk * C_ + h * DH_;
    #pragma unroll
    for (int d = 0; d < DH_; ++d) a[d] = Arow[d];
    __syncthreads();
    const float scale = 0.15811388300841898f;          // 1/sqrt(40)
    for (int c = 0; c < 80; ++c) {
        float s = 0.f;
        #pragma unroll
        for (int q = 0; q < 10; ++q) {
            float4 wv4 = *(const float4*)&wlds[c * 44 + q * 4];
            s += a[q * 4 + 0] * wv4.x + a[q * 4 + 1] * wv4.y
               + a[q * 4 + 2] * wv4.z + a[q * 4 + 3] * wv4.w;
        }
        if (!which) s *= scale;
        int n = which * 2560 + h * C_ + c0 + c;
        Bmat[(size_t)n * D_ + Dk] = f2bf(s);
    }
}

// ---------------------------------------------------------------- prep_ehs
__global__ __launch_bounds__(256) void prep_ehs(const float* __restrict__ ehs,
        const float* __restrict__ harm, unsigned short* __restrict__ ehs_bf,
        float* __restrict__ pen) {
    const int w = threadIdx.x >> 6, l = threadIdx.x & 63;
    const int kk = blockIdx.x * 4 + w, b = blockIdx.y;
    const size_t obase = ((size_t)b * KP_ + kk) * D_;
    if (kk >= KK_) {
        #pragma unroll
        for (int j = 0; j < 12; ++j) ehs_bf[obase + l + j * 64] = 0;
        if (l == 0) pen[b * KP_ + kk] = 0.f;
        return;
    }
    const float* er = ehs + ((size_t)b * KK_ + kk) * D_;
    float ss = 0.f, dd = 0.f, hh = 0.f;
    #pragma unroll
    for (int j = 0; j < 12; ++j) {
        float e = er[l + j * 64], hv = harm[l + j * 64];
        ehs_bf[obase + l + j * 64] = f2bf(e);
        ss += e * e; dd += e * hv; hh += hv * hv;
    }
    #pragma unroll
    for (int off = 32; off; off >>= 1) {
        ss += __shfl_xor(ss, off);
        dd += __shfl_xor(dd, off);
        hh += __shfl_xor(hh, off);
    }
    if (l == 0) {
        float cs = dd / (fmaxf(sqrtf(ss), EPS_) * fmaxf(sqrtf(hh), EPS_));
        pen[b * KP_ + kk] = GAMMA_ * fmaxf(cs - TAU_, 0.f);
    }
}

// ---------------------------------------------------------------- gemm_WpU
__global__ __launch_bounds__(1024) void gemm_WpU(
        const unsigned short* __restrict__ ehs_bf,
        const unsigned short* __restrict__ Bmat,
        unsigned short* __restrict__ Wp, unsigned short* __restrict__ U) {
    const int id = blockIdx.x;               // 160 = 16 b * 10 nt
    const int b = id & 15, nt = id >> 4;
    const int tid = threadIdx.x, w = tid >> 6, l = tid & 63;
    const int lrow = l & 15, lgrp = l >> 4, lk = lgrp * 8;
    __shared__ unsigned short Al[80 * 768];  // 122880 B, swizzled
    char* lds = (char*)Al;

    const unsigned short* Ag = ehs_bf + (size_t)b * KP_ * D_;
    #pragma unroll
    for (int it = 0; it < 8; ++it) {
        int ch = tid + it * 1024;
        if (ch < 7680) {
            int byte = ch * 16, row = byte / 1536;
            int a = byte ^ ((row & 7) << 4);
            *(ushort8v*)(lds + a) = *(const ushort8v*)(Ag + ch * 8);
        }
    }
    const int n0 = nt * 512 + w * 32;
    const unsigned short* Br = Bmat + (size_t)(n0 + lrow) * D_ + lk;
    bf16x8 bC[2], bN[2];
    #pragma unroll
    for (int nf = 0; nf < 2; ++nf)
        bC[nf] = *(const bf16x8*)(Br + (size_t)nf * 16 * D_);
    __syncthreads();

    f32x4 acc[5][2];
    #pragma unroll
    for (int mf = 0; mf < 5; ++mf)
        #pragma unroll
        for (int nf = 0; nf < 2; ++nf) acc[mf][nf] = (f32x4){0.f, 0.f, 0.f, 0.f};
    #pragma unroll
    for (int ks = 0; ks < D_ / 32; ++ks) {
        if (ks < D_ / 32 - 1) {
            #pragma unroll
            for (int nf = 0; nf < 2; ++nf)
                bN[nf] = *(const bf16x8*)(Br + (size_t)nf * 16 * D_ + (ks + 1) * 32);
        }
        bf16x8 af[5];
        #pragma unroll
        for (int mf = 0; mf < 5; ++mf) {
            int row = mf * 16 + lrow;
            int a = (row * 1536 + (ks * 32 + lk) * 2) ^ ((row & 7) << 4);
            af[mf] = *(const bf16x8*)(lds + a);
        }
        __builtin_amdgcn_s_setprio(1);
        #pragma unroll
        for (int mf = 0; mf < 5; ++mf)
            #pragma unroll
            for (int nf = 0; nf < 2; ++nf)
                acc[mf][nf] = __builtin_amdgcn_mfma_f32_16x16x32_bf16(
                    af[mf], bC[nf], acc[mf][nf], 0, 0, 0);
        __builtin_amdgcn_s_setprio(0);
        #pragma unroll
        for (int nf = 0; nf < 2; ++nf) bC[nf] = bN[nf];
    }
    #pragma unroll
    for (int nf = 0; nf < 2; ++nf) {
        const int col = n0 + nf * 16 + lrow;
        if (col < 2560) {
            const int h = col / C_, c = col % C_;
            #pragma unroll
            for (int mf = 0; mf < 5; ++mf)
                #pragma unroll
                for (int r = 0; r < 4; ++r) {
                    int kk = mf * 16 + lgrp * 4 + r;
                    Wp[((size_t)b * NP_ + h * KP_ + kk) * C_ + c] = f2bf(acc[mf][nf][r]);
                }
        } else {
            const int n2 = col - 2560;
            const int h = n2 / C_, c = n2 % C_;
            #pragma unroll
            for (int mf = 0; mf < 5; ++mf)
                #pragma unroll
                for (int r = 0; r < 4; ++r) {
                    int kk = mf * 16 + lgrp * 4 + r;
                    U[((size_t)b * C_ + c) * NP_ + h * KP_ + kk] = f2bf(acc[mf][nf][r]);
                }
        }
    }
}

// ---------------------------------------------------------------- fused attn
// 1024 blocks x 1024 threads, 64 S-rows, 160KB LDS.
// Phase 1: HS 40KB + 3x40KB Wp bufs (depth-2). Phase 2: PB 80KB (overlays
// WB0+WB1) + 4x20KB U bufs (depth-3), R7 register profile (no held P regs).
__global__ __launch_bounds__(1024) void fused_attn(
        const float* __restrict__ hs, const unsigned short* __restrict__ Wp,
        const unsigned short* __restrict__ U, const float* __restrict__ pen,
        const float* __restrict__ bo, float* __restrict__ out) {
    const int id = blockIdx.x;                  // 1024 = 8 xcd * 128
    const int xcd = id & 7, rest = id >> 3;
    const int b = xcd * 2 + (rest >> 6);        // 2 batches per XCD
    const int s0 = (rest & 63) * 64;
    __shared__ __align__(16) char smem[163840];
    char* HS  = smem;                           // 40KB: phase-1 hs tile
    char* WB0 = smem + 40960;                   // Wp slice bufs 3x40KB
    char* WB1 = smem + 81920;
    char* WB2 = smem + 122880;
    char* PB  = smem + 40960;                   // P [64][640] 80KB (over WB0+WB1)
    char* UB[4];                                // U slice bufs 4x20KB
    UB[0] = smem;          UB[1] = smem + 20480;
    UB[2] = smem + 122880; UB[3] = smem + 143360;
    const int tid = threadIdx.x, w = tid >> 6, l = tid & 63;
    const int lrow = l & 15, lgrp = l >> 4, lk = lgrp * 8;
    const int h = w & 7, mh = w >> 3;           // phase-1 roles
    const int mgrp = w & 3, ngrp = w >> 2;      // phase-2 roles

    const unsigned short* Wpb = Wp + (size_t)b * NP_ * C_;
    const unsigned short* Ub  = U  + (size_t)b * C_ * NP_;

    // Wp K=32 slice -> [n 640][4 chunks 16B], chunk swz ^((n>>1)&3) on source.
    // per-wave DMA insts: 3 (w<8) / 2 (w>=8)
    auto stage_wp = [&](int ks, char* buf) {
        #pragma unroll
        for (int j = 0; j < 2; ++j) {
            int L = w * 128 + j * 64 + l;       // 0..2047
            int n = L >> 2, cs = (L & 3) ^ ((n >> 1) & 3);
            gld16(Wpb + (size_t)n * C_ + ks * 32 + cs * 8,
                  buf + (w * 128 + j * 64) * 16);
        }
        if (w < 8) {
            int L = 2048 + w * 64 + l;          // 2048..2559
            int n = L >> 2, cs = (L & 3) ^ ((n >> 1) & 3);
            gld16(Wpb + (size_t)n * C_ + ks * 32 + cs * 8,
                  buf + (2048 + w * 64) * 16);
        }
    };
    // U K=32 slice -> [c 320][4 chunks 16B], chunk swz ^((c>>1)&3) on source.
    // per-wave DMA insts: 2 (w<4) / 1 (w>=4)
    auto stage_u = [&](int ksn, char* buf) {
        {
            int L = w * 64 + l;                 // 0..1023
            int c = L >> 2, cs = (L & 3) ^ ((c >> 1) & 3);
            gld16(Ub + (size_t)c * NP_ + ksn * 32 + cs * 8, buf + (w * 64) * 16);
        }
        if (w < 4) {
            int L = 1024 + w * 64 + l;          // 1024..1279
            int c = L >> 2, cs = (L & 3) ^ ((c >> 1) & 3);
            gld16(Ub + (size_t)c * NP_ + ksn * 32 + cs * 8,
                  buf + (1024 + w * 64) * 16);
        }
    };

    // ---- prologue: DMA slices 0..2, then pen + hs staging under the DMA
    stage_wp(0, WB0);
    stage_wp(1, WB1);
    stage_wp(2, WB2);
    float4 pv4[5];
    #pragma unroll
    for (int nf = 0; nf < 5; ++nf)
        pv4[nf] = *(const float4*)(pen + b * KP_ + nf * 16 + lgrp * 4);
    const float4* hv = (const float4*)(hs + ((size_t)b * S_ + s0) * C_);
    #pragma unroll
    for (int it = 0; it < 5; ++it) {            // 5*1024 = 5120 float4 = 64x320 f32
        int i = tid + it * 1024;
        float4 v = hv[i];
        int r = i / 80, c = (i * 4) % C_;
        ushort4 u;
        u.x = f2bf(v.x); u.y = f2bf(v.y); u.z = f2bf(v.z); u.w = f2bf(v.w);
        int a = (r * 640 + c * 2) ^ ((r & 7) << 4);
        *(ushort4*)(HS + a) = u;
    }
    #pragma unroll
    for (int nf = 0; nf < 5; ++nf)              // retire pen loads (vmcnt purity)
        asm volatile("" :: "v"(pv4[nf].x), "v"(pv4[nf].y),
                           "v"(pv4[nf].z), "v"(pv4[nf].w));
    if (w < 8) { WAITVL(6); } else { WAITVL(4); }   // slice0 landed + ds_writes done
    BAR();

    // ---- phase 1: D[kk][m] over 10 K-slices, 3-buf depth-2 pipeline
    f32x4 acc[5][2];
    #pragma unroll
    for (int nf = 0; nf < 5; ++nf)
        #pragma unroll
        for (int mf = 0; mf < 2; ++mf) acc[nf][mf] = (f32x4){0.f, 0.f, 0.f, 0.f};
    #pragma unroll
    for (int ks = 0; ks < 10; ++ks) {
        char* wb = (ks % 3 == 0) ? WB0 : (ks % 3 == 1) ? WB1 : WB2;
        bf16x8 bC[5], hf[2];
        #pragma unroll
        for (int nf = 0; nf < 5; ++nf) {
            int n = h * KP_ + nf * 16 + lrow;
            bC[nf] = *(const bf16x8*)(wb + n * 64 + ((lgrp ^ ((n >> 1) & 3)) << 4));
        }
        #pragma unroll
        for (int mf = 0; mf < 2; ++mf) {
            int row = mh * 32 + mf * 16 + lrow;
            int a = (row * 640 + (ks * 32 + lk) * 2) ^ ((row & 7) << 4);
            hf[mf] = *(const bf16x8*)(HS + a);
        }
        WAITLG();
        BAR();                                  // all waves done reading wb (+HS @9)
        if (ks < 7) stage_wp(ks + 3, wb);       // depth-2 refill
        __builtin_amdgcn_s_setprio(1);
        #pragma unroll
        for (int nf = 0; nf < 5; ++nf)
            #pragma unroll
            for (int mf = 0; mf < 2; ++mf)
                acc[nf][mf] = __builtin_amdgcn_mfma_f32_16x16x32_bf16(
                    bC[nf], hf[mf], acc[nf][mf], 0, 0, 0);
        __builtin_amdgcn_s_setprio(0);
        if (ks < 9) {
            if (ks < 7)      { if (w < 8) { WAITV(6); } else { WAITV(4); } }
            else if (ks == 7){ if (w < 8) { WAITV(3); } else { WAITV(2); } }
            else             { WAITV(0); }
            BAR();                              // slice ks+1 visible to all
        }
    }
    // ks=9's read-barrier already certified HS + all WB bufs free.

    // ---- transition: stage U slices 0..3; softmax + P write overlap the DMA
    stage_u(0, UB[0]);
    stage_u(1, UB[1]);
    stage_u(2, UB[2]);
    stage_u(3, UB[3]);

    float inv2[2];
    #pragma unroll
    for (int mf = 0; mf < 2; ++mf) {
        float mx = -1e30f;
        #pragma unroll
        for (int nf = 0; nf < 5; ++nf)
            #pragma unroll
            for (int r = 0; r < 4; ++r) {
                float x = acc[nf][mf][r] - ((const float*)&pv4[nf])[r];
                if (nf == 4 && r >= 1) x = (lgrp == 3) ? -1e30f : x;  // kk 77..79
                acc[nf][mf][r] = x;
                mx = fmaxf(mx, x);
            }
        mx = fmaxf(mx, __shfl_xor(mx, 16));
        mx = fmaxf(mx, __shfl_xor(mx, 32));
        float s = 0.f;
        #pragma unroll
        for (int nf = 0; nf < 5; ++nf)
            #pragma unroll
            for (int r = 0; r < 4; ++r) {
                float e = __expf(acc[nf][mf][r] - mx);
                acc[nf][mf][r] = e; s += e;
            }
        s += __shfl_xor(s, 16);
        s += __shfl_xor(s, 32);
        inv2[mf] = 1.f / s;
    }

    // write P (bf16) into PB: byte = (m*1280 + col*2) ^ ((m&7)<<4)
    #pragma unroll
    for (int mf = 0; mf < 2; ++mf) {
        const int m = mh * 32 + mf * 16 + lrow;
        const float inv = inv2[mf];
        #pragma unroll
        for (int nf = 0; nf < 5; ++nf) {
            ushort4 u;
            u.x = f2bf(acc[nf][mf][0] * inv);
            u.y = f2bf(acc[nf][mf][1] * inv);
            u.z = f2bf(acc[nf][mf][2] * inv);
            u.w = f2bf(acc[nf][mf][3] * inv);
            int a = (m * 1280 + (h * KP_ + nf * 16 + lgrp * 4) * 2) ^ ((m & 7) << 4);
            *(ushort4*)(PB + a) = u;
        }
    }
    if (w < 4) { WAITVL(6); } else { WAITVL(3); }   // U slice0 landed + P visible
    BAR();

    // ---- phase 2: out = P @ U + bo over 20 K=32 slices, 4-buf depth-3
    f32x4 acc2[5];
    #pragma unroll
    for (int nf = 0; nf < 5; ++nf) acc2[nf] = (f32x4){0.f, 0.f, 0.f, 0.f};
    #pragma unroll
    for (int t = 0; t < 20; ++t) {
        char* ub = UB[t & 3];
        bf16x8 pa, uf[5];
        {
            int m = mgrp * 16 + lrow;
            int a = (m * 1280 + (t * 32 + lk) * 2) ^ ((m & 7) << 4);
            pa = *(const bf16x8*)(PB + a);
        }
        #pragma unroll
        for (int nf = 0; nf < 5; ++nf) {
            int c = ngrp * KP_ + nf * 16 + lrow;
            uf[nf] = *(const bf16x8*)(ub + c * 64 + ((lgrp ^ ((c >> 1) & 3)) << 4));
        }
        WAITLG();
        BAR();                                  // all waves done reading ub
        if (t < 16) stage_u(t + 4, ub);         // depth-3 refill
        __builtin_amdgcn_s_setprio(1);
        #pragma unroll
        for (int nf = 0; nf < 5; ++nf)
            acc2[nf] = __builtin_amdgcn_mfma_f32_16x16x32_bf16(pa, uf[nf], acc2[nf], 0, 0, 0);
        __builtin_amdgcn_s_setprio(0);
        if (t < 19) {
            if (t < 16)       { if (w < 4) { WAITV(6); } else { WAITV(3); } }
            else if (t == 16) { if (w < 4) { WAITV(4); } else { WAITV(2); } }
            else if (t == 17) { if (w < 4) { WAITV(2); } else { WAITV(1); } }
            else              { WAITV(0); }
            BAR();                              // slice t+1 visible to all
        }
    }

    // ---- epilogue
    float bov[5];
    #pragma unroll
    for (int nf = 0; nf < 5; ++nf) bov[nf] = bo[ngrp * KP_ + nf * 16 + lrow];
    float* op = out + ((size_t)b * S_ + s0) * C_;
    #pragma unroll
    for (int r = 0; r < 4; ++r)
        #pragma unroll
        for (int nf = 0; nf < 5; ++nf)
            op[(size_t)(mgrp * 16 + lgrp * 4 + r) * C_ +
               ngrp * KP_ + nf * 16 + lrow] = acc2[nf][r] + bov[nf];
}

// ---------------------------------------------------------------- launch
extern "C" void kernel_launch(void* const* d_in, const int* in_sizes, int n_in,
                              void* d_out, int out_size, void* d_ws, size_t ws_size,
                              hipStream_t stream) {
    const float* hs   = (const float*)d_in[0];
    const float* ehs  = (const float*)d_in[1];
    const float* harm = (const float*)d_in[2];
    const float* Wq   = (const float*)d_in[3];
    const float* Wk   = (const float*)d_in[4];
    const float* Wv   = (const float*)d_in[5];
    const float* Wo   = (const float*)d_in[6];
    const float* bo   = (const float*)d_in[7];
    float* out = (float*)d_out;

    char* ws = (char*)d_ws;
    unsigned short* ehs_bf = (unsigned short*)(ws);             //  1,966,080
    unsigned short* Bmat   = (unsigned short*)(ws + 1966080);   //  7,864,320
    float*          pen    = (float*)        (ws + 9830400);    //      5,120
    unsigned short* Wp     = (unsigned short*)(ws + 9835520);   //  6,553,600
    unsigned short* U      = (unsigned short*)(ws + 16389120);  //  6,553,600

    build_M <<<dim3(3, 8, 8),  256, 0, stream>>>(Wq, Wk, Wv, Wo, Bmat);
    prep_ehs<<<dim3(20, 16),   256, 0, stream>>>(ehs, harm, ehs_bf, pen);
    gemm_WpU<<<dim3(160),     1024, 0, stream>>>(ehs_bf, Bmat, Wp, U);
    fused_attn<<<dim3(1024),  1024, 0, stream>>>(hs, Wp, U, pen, bo, out);
}